// Round 5
// baseline (4787.275 us; speedup 1.0000x reference)
//
#include <hip/hip_runtime.h>

#define R_ET 8
#define DH 128

typedef __bf16 bf16x8 __attribute__((ext_vector_type(8)));
typedef float f32x4 __attribute__((ext_vector_type(4)));

__device__ __forceinline__ ushort f2bf(float f) {
  unsigned u = __float_as_uint(f);
  u += 0x7fff + ((u >> 16) & 1);  // round-to-nearest-even
  return (ushort)(u >> 16);
}

// Swizzled activation/weight layout: element (row, k) lives at
//   row*128 + ((k>>3) ^ (row&7))*8 + (k&7)
// (ushort units for bf16 buffers, float units for the LDS fp32 agg tile).
//
// r3 lesson: global-atomic cost scales with RMWs-per-cache-line (<=32/line free,
// >=30K/line catastrophic). count/place below stay at the proven ~32/line profile.
// r4 lesson: the t-slab (x*W_r for all N,r; 102MB) round-trip was the structural
// floor (~110us/layer). This version aggregates x per (dst,r) in LDS and applies
// W_r immediately -- t never exists.

// ---------------- degree count per (r, dst) segment ----------------
__global__ void count_kernel(const int* __restrict__ ei, const int* __restrict__ et,
                             int* __restrict__ cnt, int E, int N) {
  int e = blockIdx.x * blockDim.x + threadIdx.x;
  if (e < E) atomicAdd(&cnt[et[e] * N + ei[E + e]], 1);
}

// ---------------- 3-phase exclusive scan over M = N*R segment counts ----------------
__global__ __launch_bounds__(1024) void scanA(const int* __restrict__ cnt,
                                              int* __restrict__ off,
                                              int* __restrict__ bsum, int M) {
  __shared__ int s[1024];
  int tid = threadIdx.x;
  int i = blockIdx.x * 1024 + tid;
  int d = (i < M) ? cnt[i] : 0;
  s[tid] = d;
  __syncthreads();
  for (int st = 1; st < 1024; st <<= 1) {
    int v = (tid >= st) ? s[tid - st] : 0;
    __syncthreads();
    s[tid] += v;
    __syncthreads();
  }
  if (i < M) off[i] = s[tid] - d;
  if (tid == 1023) bsum[blockIdx.x] = s[1023];
}

__global__ __launch_bounds__(1024) void scanB(int* __restrict__ bsum, int nb) {
  __shared__ int s[1024];
  int tid = threadIdx.x;
  int v = (tid < nb) ? bsum[tid] : 0;
  s[tid] = v;
  __syncthreads();
  for (int st = 1; st < 1024; st <<= 1) {
    int x = (tid >= st) ? s[tid - st] : 0;
    __syncthreads();
    s[tid] += x;
    __syncthreads();
  }
  if (tid < nb) bsum[tid] = s[tid] - v;
}

__global__ __launch_bounds__(1024) void scanC(int* __restrict__ off,
                                              int* __restrict__ cursor,
                                              const int* __restrict__ bsum,
                                              int M, int E) {
  int i = blockIdx.x * 1024 + threadIdx.x;
  if (i < M) {
    int o = off[i] + bsum[blockIdx.x];
    off[i] = o;
    cursor[i] = o;
  }
  if (i == 0) off[M] = E;
}

// ---------------- place edges into (r, dst)-sorted slots ----------------
// meta: x = src | dstLow<<16 (requires N <= 65536), y = 1/cnt(dst,r)
__global__ void place_kernel(const int* __restrict__ ei, const int* __restrict__ et,
                             const int* __restrict__ cnt, int* __restrict__ cursor,
                             int2* __restrict__ meta, int E, int N) {
  int e = blockIdx.x * blockDim.x + threadIdx.x;
  if (e >= E) return;
  int src = ei[e], dst = ei[E + e], r = et[e];
  int seg = r * N + dst;
  int slot = atomicAdd(&cursor[seg], 1);
  meta[slot] = make_int2(src | ((dst & 127) << 16),
                         __float_as_int(1.f / (float)cnt[seg]));
}

// ---------------- weight convert+transpose: Wt[mat][n][k] bf16, swizzled ----------------
__global__ __launch_bounds__(256) void wconv_kernel(const float* __restrict__ root,
                                                    const float* __restrict__ W,
                                                    ushort* __restrict__ Wt) {
  int mat = blockIdx.x;  // 0 = root, 1..8 = W[r]
  const float* src = (mat == 0) ? root : (W + (size_t)(mat - 1) * DH * DH);
  ushort* dst = Wt + (size_t)mat * DH * DH;
  for (int idx = threadIdx.x; idx < DH * DH; idx += 256) {
    int n = idx >> 7, k = idx & 127;
    dst[n * DH + (((k >> 3) ^ (n & 7)) << 3) + (k & 7)] = f2bf(src[k * DH + n]);
  }
}

// ---------------- activation convert (layer 0), zero-pads rows, swizzled ----------------
__global__ __launch_bounds__(256) void aconv_kernel(const float* __restrict__ src,
                                                    ushort* __restrict__ dst,
                                                    int total, int padtotal) {
  int i4 = (blockIdx.x * 256 + threadIdx.x) * 4;
  if (i4 >= padtotal) return;
  int row = i4 >> 7, k = i4 & 127;
  ushort4 o = make_ushort4(0, 0, 0, 0);
  if (i4 < total) {
    float4 v = *(const float4*)&src[i4];
    o = make_ushort4(f2bf(v.x), f2bf(v.y), f2bf(v.z), f2bf(v.w));
  }
  *(ushort4*)&dst[(size_t)row * DH + (((k >> 3) ^ (row & 7)) << 3) + (k & 7)] = o;
}

// ================= fused RGCN layer: root GEMM + per-relation LDS aggregate+GEMM ====
// Block owns 128 dst rows. LDS: 64KB fp32 agg tile (low 32KB doubles as bf16 As
// during the root GEMM). Per relation r: zero agg -> stream the contiguous
// (r, dst-tile) edge run (4-unrolled, LDS f32 atomics) -> GEMM agg x W_r from LDS.
// Weights read per-fragment from global (L2-hot, 288KB total). Output stays in acc
// regs across all 9 GEMMs; epilogue writes next-layer activations (swizzled bf16)
// or per-block pool partials (last layer; bias folded into mlp).
__global__ __launch_bounds__(256, 2) void rgcn_layer(
    const ushort* __restrict__ Ain, const int* __restrict__ off2,
    const int2* __restrict__ meta, const ushort* __restrict__ Wt,
    const float* __restrict__ bias, ushort* __restrict__ Aout,
    float* __restrict__ pbuf, int N, int last) {
  __shared__ __align__(16) float agg[128 * DH];  // 64 KB
  __shared__ float sb[DH];
  ushort* As = (ushort*)agg;
  const int tid = threadIdx.x;
  const int wave = tid >> 6, lane = tid & 63;
  const int quad = lane >> 4, l15 = lane & 15;
  const int rbase = blockIdx.x * 128;
  const int wr = (wave >> 1) * 64, wc = (wave & 1) * 64;
  const int kb = lane >> 2;            // (k>>3) for k = lane*2
  const int klo = (lane * 2) & 7;      // (k&7)

  // ---- stage As (this tile's activations) for the root GEMM ----
  const ushort* gA = Ain + (size_t)rbase * DH;
#pragma unroll
  for (int it = 0; it < 8; it++) {
    __builtin_amdgcn_global_load_lds(
        (const __attribute__((address_space(1))) void*)(gA + (it * 256 + tid) * 8),
        (__attribute__((address_space(3))) void*)(As + (it * 256 + wave * 64) * 8), 16, 0, 0);
  }
  __syncthreads();

  f32x4 acc[4][4];
#pragma unroll
  for (int i = 0; i < 4; i++)
#pragma unroll
    for (int j = 0; j < 4; j++) acc[i][j] = (f32x4){0.f, 0.f, 0.f, 0.f};

  // ---- root GEMM ----
#pragma unroll
  for (int kc = 0; kc < 4; kc++) {
    bf16x8 af[4], bfr[4];
#pragma unroll
    for (int i = 0; i < 4; i++) {
      int ra = wr + i * 16 + l15;
      int rb = wc + i * 16 + l15;
      af[i] = *(const bf16x8*)&As[ra * DH + (((kc * 4 + quad) ^ (ra & 7)) << 3)];
      bfr[i] = *(const bf16x8*)&Wt[rb * DH + (((kc * 4 + quad) ^ (rb & 7)) << 3)];
    }
#pragma unroll
    for (int i = 0; i < 4; i++)
#pragma unroll
      for (int j = 0; j < 4; j++)
        acc[i][j] = __builtin_amdgcn_mfma_f32_16x16x32_bf16(bfr[j], af[i], acc[i][j], 0, 0, 0);
  }
  __syncthreads();  // done reading As; agg region free

  const int rend = min(rbase + 128, N);

  for (int r = 0; r < R_ET; r++) {
    // zero agg (16K floats)
#pragma unroll
    for (int it = 0; it < 16; it++)
      *(f32x4*)&agg[(it * 256 + tid) * 4] = (f32x4){0.f, 0.f, 0.f, 0.f};
    __syncthreads();

    // stream this relation's edge run for the tile (contiguous; 4-unrolled)
    const int start = off2[r * N + rbase];
    const int end = off2[r * N + rend];
    for (int base = start + wave * 64; base < end; base += 256) {
      int m = min(64, end - base);
      int2 md = make_int2(0, 0);
      if (lane < m) md = meta[base + lane];
      int j = 0;
      for (; j + 4 <= m; j += 4) {
        int p0 = __shfl(md.x, j),     q0 = __shfl(md.y, j);
        int p1 = __shfl(md.x, j + 1), q1 = __shfl(md.y, j + 1);
        int p2 = __shfl(md.x, j + 2), q2 = __shfl(md.y, j + 2);
        int p3 = __shfl(md.x, j + 3), q3 = __shfl(md.y, j + 3);
        int s0 = p0 & 0xffff, s1 = p1 & 0xffff, s2 = p2 & 0xffff, s3 = p3 & 0xffff;
        unsigned v0 = *(const unsigned*)&Ain[((size_t)s0 << 7) + ((kb ^ (s0 & 7)) << 3) + klo];
        unsigned v1 = *(const unsigned*)&Ain[((size_t)s1 << 7) + ((kb ^ (s1 & 7)) << 3) + klo];
        unsigned v2 = *(const unsigned*)&Ain[((size_t)s2 << 7) + ((kb ^ (s2 & 7)) << 3) + klo];
        unsigned v3 = *(const unsigned*)&Ain[((size_t)s3 << 7) + ((kb ^ (s3 & 7)) << 3) + klo];
        int d0 = (p0 >> 16) & 127, d1 = (p1 >> 16) & 127;
        int d2 = (p2 >> 16) & 127, d3 = (p3 >> 16) & 127;
        int o0 = d0 * DH + ((kb ^ (d0 & 7)) << 3) + klo;
        int o1 = d1 * DH + ((kb ^ (d1 & 7)) << 3) + klo;
        int o2 = d2 * DH + ((kb ^ (d2 & 7)) << 3) + klo;
        int o3 = d3 * DH + ((kb ^ (d3 & 7)) << 3) + klo;
        float c0 = __int_as_float(q0), c1 = __int_as_float(q1);
        float c2 = __int_as_float(q2), c3 = __int_as_float(q3);
        atomicAdd(&agg[o0], __uint_as_float(v0 << 16) * c0);
        atomicAdd(&agg[o0 + 1], __uint_as_float(v0 & 0xffff0000u) * c0);
        atomicAdd(&agg[o1], __uint_as_float(v1 << 16) * c1);
        atomicAdd(&agg[o1 + 1], __uint_as_float(v1 & 0xffff0000u) * c1);
        atomicAdd(&agg[o2], __uint_as_float(v2 << 16) * c2);
        atomicAdd(&agg[o2 + 1], __uint_as_float(v2 & 0xffff0000u) * c2);
        atomicAdd(&agg[o3], __uint_as_float(v3 << 16) * c3);
        atomicAdd(&agg[o3 + 1], __uint_as_float(v3 & 0xffff0000u) * c3);
      }
      for (; j < m; j++) {
        int p = __shfl(md.x, j);
        float c = __int_as_float(__shfl(md.y, j));
        int s = p & 0xffff, d = (p >> 16) & 127;
        unsigned v = *(const unsigned*)&Ain[((size_t)s << 7) + ((kb ^ (s & 7)) << 3) + klo];
        int o = d * DH + ((kb ^ (d & 7)) << 3) + klo;
        atomicAdd(&agg[o], __uint_as_float(v << 16) * c);
        atomicAdd(&agg[o + 1], __uint_as_float(v & 0xffff0000u) * c);
      }
    }
    __syncthreads();

    // GEMM: acc += agg (fp32 LDS, swizzled) x W_r
    const ushort* Wr = Wt + (size_t)(r + 1) * DH * DH;
#pragma unroll
    for (int kc = 0; kc < 4; kc++) {
      bf16x8 af[4], bfr[4];
#pragma unroll
      for (int i = 0; i < 4; i++) {
        int ra = wr + i * 16 + l15;
        const float* ap = &agg[ra * DH + (((kc * 4 + quad) ^ (ra & 7)) << 3)];
        f32x4 a0 = *(const f32x4*)ap;
        f32x4 a1 = *(const f32x4*)(ap + 4);
        bf16x8 t;
        t[0] = (__bf16)a0[0]; t[1] = (__bf16)a0[1];
        t[2] = (__bf16)a0[2]; t[3] = (__bf16)a0[3];
        t[4] = (__bf16)a1[0]; t[5] = (__bf16)a1[1];
        t[6] = (__bf16)a1[2]; t[7] = (__bf16)a1[3];
        af[i] = t;
        int rb = wc + i * 16 + l15;
        bfr[i] = *(const bf16x8*)&Wr[rb * DH + (((kc * 4 + quad) ^ (rb & 7)) << 3)];
      }
#pragma unroll
      for (int i = 0; i < 4; i++)
#pragma unroll
        for (int j = 0; j < 4; j++)
          acc[i][j] = __builtin_amdgcn_mfma_f32_16x16x32_bf16(bfr[j], af[i], acc[i][j], 0, 0, 0);
    }
    __syncthreads();  // all GEMM reads done before next zero
  }

  // ---- epilogue ----
  if (!last) {
#pragma unroll
    for (int i = 0; i < 4; i++) {
      int node = rbase + wr + i * 16 + l15;
      bool ok = node < N;
#pragma unroll
      for (int j = 0; j < 4; j++) {
        int c0 = wc + j * 16 + quad * 4;
        float4 bv = *(const float4*)&bias[c0];
        unsigned lo = 0, hi = 0;
        if (ok) {
          lo = (unsigned)f2bf(fmaxf(acc[i][j][0] + bv.x, 0.f)) |
               ((unsigned)f2bf(fmaxf(acc[i][j][1] + bv.y, 0.f)) << 16);
          hi = (unsigned)f2bf(fmaxf(acc[i][j][2] + bv.z, 0.f)) |
               ((unsigned)f2bf(fmaxf(acc[i][j][3] + bv.w, 0.f)) << 16);
        }
        *(uint2*)&Aout[(size_t)node * DH + (((c0 >> 3) ^ (node & 7)) << 3) + (c0 & 7)] =
            make_uint2(lo, hi);  // pad rows (node >= N) get zeros
      }
    }
  } else {
    // column partial sums for the mean pool (bias added in mlp)
    if (tid < DH) sb[tid] = 0.f;
    __syncthreads();
#pragma unroll
    for (int j = 0; j < 4; j++) {
      f32x4 sj;
#pragma unroll
      for (int c = 0; c < 4; c++)
        sj[c] = acc[0][j][c] + acc[1][j][c] + acc[2][j][c] + acc[3][j][c];
#pragma unroll
      for (int mask = 1; mask < 16; mask <<= 1)
#pragma unroll
        for (int c = 0; c < 4; c++) sj[c] += __shfl_xor(sj[c], mask);
      if (l15 == 0) {
        int c0 = wc + j * 16 + quad * 4;
#pragma unroll
        for (int c = 0; c < 4; c++) atomicAdd(&sb[c0 + c], sj[c]);
      }
    }
    __syncthreads();
    if (tid < DH) pbuf[(size_t)blockIdx.x * DH + tid] = sb[tid];
  }
}

// ---------------- reduce per-block partials -> u ----------------
__global__ __launch_bounds__(256) void pool_reduce(const float* __restrict__ pbuf,
                                                   float* __restrict__ u, int nblk) {
  __shared__ float s[256];
  int tid = threadIdx.x;
  int c = tid & 127, h = tid >> 7;
  int chunk = (nblk + gridDim.x - 1) / gridDim.x;
  int r0 = blockIdx.x * chunk;
  int r1 = min(r0 + chunk, nblk);
  float sum = 0.f;
  for (int r = r0 + h; r < r1; r += 2) sum += pbuf[(size_t)r * 128 + c];
  s[tid] = sum;
  __syncthreads();
  if (tid < 128) atomicAdd(&u[c], s[tid] + s[tid + 128]);
}

// ---------------- final MLP on concat(u1/N + b2, u2/N + b2) ----------------
__global__ __launch_bounds__(256) void mlp_kernel(
    const float* __restrict__ u, const float* __restrict__ b2,
    const float* __restrict__ fc1w, const float* __restrict__ fc1b,
    const float* __restrict__ fc2w, const float* __restrict__ fc2b,
    float* __restrict__ out, int N) {
  __shared__ float uin[256];
  __shared__ float hred[128];
  int tid = threadIdx.x;
  uin[tid] = u[tid] * (1.f / (float)N) + b2[tid & 127];
  __syncthreads();
  if (tid < 128) {
    float s = fc1b[tid];
    for (int i = 0; i < 256; i++) s = fmaf(uin[i], fc1w[i * 128 + tid], s);
    s = fmaxf(s, 0.f);
    hred[tid] = s * fc2w[tid];
  }
  __syncthreads();
  if (tid == 0) {
    float s = fc2b[0];
    for (int i = 0; i < 128; i++) s += hred[i];
    out[0] = s;
  }
}

extern "C" void kernel_launch(void* const* d_in, const int* in_sizes, int n_in,
                              void* d_out, int out_size, void* d_ws, size_t ws_size,
                              hipStream_t stream) {
  const float* x[2] = {(const float*)d_in[0], (const float*)d_in[3]};
  const int* ei[2] = {(const int*)d_in[1], (const int*)d_in[4]};
  const int* et[2] = {(const int*)d_in[2], (const int*)d_in[5]};
  const float* Wp[3] = {(const float*)d_in[6], (const float*)d_in[9], (const float*)d_in[12]};
  const float* rootp[3] = {(const float*)d_in[7], (const float*)d_in[10], (const float*)d_in[13]};
  const float* biasp[3] = {(const float*)d_in[8], (const float*)d_in[11], (const float*)d_in[14]};
  const float* fc1w = (const float*)d_in[15];
  const float* fc1b = (const float*)d_in[16];
  const float* fc2w = (const float*)d_in[17];
  const float* fc2b = (const float*)d_in[18];

  const int N = in_sizes[0] / DH;  // meta packing requires N <= 65536 (harness: 50000)
  const int E = in_sizes[2];
  const int Npad = (N + 127) & ~127;
  const int nt = Npad / 128;            // dst tiles / rgcn_layer blocks
  const int M = N * R_ET;               // (r, dst) segments
  const int MB = (M + 1023) / 1024;     // scan blocks (<=1024)

  char* ws = (char*)d_ws;
  size_t ob = 0;
  auto alloc = [&](size_t bytes) {
    void* p = ws + ob;
    ob = (ob + bytes + 255) & ~(size_t)255;
    return p;
  };
  int* cnt2 = (int*)alloc((size_t)M * 4);
  int* off2 = (int*)alloc((size_t)(M + 1) * 4);
  int* cursor2 = (int*)alloc((size_t)M * 4);
  int* bsum = (int*)alloc(1024 * 4);
  int2* meta = (int2*)alloc((size_t)E * 8);
  float* u = (float*)alloc(1024);
  float* pbuf = (float*)alloc((size_t)nt * DH * 4);
  ushort* A0 = (ushort*)alloc((size_t)Npad * DH * 2);
  ushort* A1 = (ushort*)alloc((size_t)Npad * DH * 2);
  ushort* Wt = (ushort*)alloc((size_t)3 * 9 * DH * DH * 2);
  (void)ws_size;

  hipMemsetAsync(u, 0, 2 * DH * sizeof(float), stream);
  for (int l = 0; l < 3; l++)
    wconv_kernel<<<9, 256, 0, stream>>>(rootp[l], Wp[l], Wt + (size_t)l * 9 * DH * DH);

  dim3 egrid((E + 255) / 256);
  const int total = N * DH, padtotal = Npad * DH;
  dim3 agrid((padtotal / 4 + 255) / 256);

  for (int g = 0; g < 2; g++) {
    hipMemsetAsync(cnt2, 0, (size_t)M * sizeof(int), stream);
    count_kernel<<<egrid, 256, 0, stream>>>(ei[g], et[g], cnt2, E, N);
    scanA<<<MB, 1024, 0, stream>>>(cnt2, off2, bsum, M);
    scanB<<<1, 1024, 0, stream>>>(bsum, MB);
    scanC<<<MB, 1024, 0, stream>>>(off2, cursor2, bsum, M, E);
    place_kernel<<<egrid, 256, 0, stream>>>(ei[g], et[g], cnt2, cursor2, meta, E, N);
    aconv_kernel<<<agrid, 256, 0, stream>>>(x[g], A0, total, padtotal);

    rgcn_layer<<<nt, 256, 0, stream>>>(A0, off2, meta, Wt, biasp[0], A1, nullptr, N, 0);
    rgcn_layer<<<nt, 256, 0, stream>>>(A1, off2, meta, Wt + (size_t)9 * DH * DH,
                                       biasp[1], A0, nullptr, N, 0);
    rgcn_layer<<<nt, 256, 0, stream>>>(A0, off2, meta, Wt + (size_t)18 * DH * DH,
                                       biasp[2], nullptr, pbuf, N, 1);
    pool_reduce<<<100, 256, 0, stream>>>(pbuf, u + g * DH, nt);
  }
  mlp_kernel<<<1, 256, 0, stream>>>(u, biasp[2], fc1w, fc1b, fc2w, fc2b,
                                    (float*)d_out, N);
}

// Round 6
// 1317.313 us; speedup vs baseline: 3.6341x; 3.6341x over previous
//
#include <hip/hip_runtime.h>

#define R_ET 8
#define DH 128
#define KST 1152  // 8 relation blocks + root block, each 128 wide

typedef __bf16 bf16x8 __attribute__((ext_vector_type(8)));
typedef float f32x4 __attribute__((ext_vector_type(4)));

__device__ __forceinline__ ushort f2bf(float f) {
  unsigned u = __float_as_uint(f);
  u += 0x7fff + ((u >> 16) & 1);  // round-to-nearest-even
  return (ushort)(u >> 16);
}

// Swizzled layouts: element (row, k) lives at row*W + ((k>>3)^(row&7))*8 + (k&7).
// Activations W=128; stacked weights / G-tile W=1152 (XOR touches only low 3 bits
// of the 16B-block index, so each 128-col block swizzles internally).
//
// r3 lesson: global-atomic cost scales with RMWs-per-cache-line (~32/line free).
// r5 lesson: fused per-tile edge streaming at 391 blocks = TLP collapse (755us,
// all pipes <4%). This version: 1563 blocks x 8 waves, per-wave register
// aggregation (no LDS atomics), src reads hit the L3-resident 12.8MB A-buffer.

// ---------------- degree count per (dst, etype) segment ----------------
__global__ void count_kernel(const int* __restrict__ ei, const int* __restrict__ et,
                             int* __restrict__ cnt, int E) {
  int e = blockIdx.x * blockDim.x + threadIdx.x;
  if (e < E) atomicAdd(&cnt[ei[E + e] * R_ET + et[e]], 1);
}

// ---------------- 3-phase exclusive scan over M = N*R segment counts ----------------
__global__ __launch_bounds__(1024) void scanA(const int* __restrict__ cnt,
                                              int* __restrict__ off,
                                              int* __restrict__ bsum, int M) {
  __shared__ int s[1024];
  int tid = threadIdx.x;
  int i = blockIdx.x * 1024 + tid;
  int d = (i < M) ? cnt[i] : 0;
  s[tid] = d;
  __syncthreads();
  for (int st = 1; st < 1024; st <<= 1) {
    int v = (tid >= st) ? s[tid - st] : 0;
    __syncthreads();
    s[tid] += v;
    __syncthreads();
  }
  if (i < M) off[i] = s[tid] - d;
  if (tid == 1023) bsum[blockIdx.x] = s[1023];
}

__global__ __launch_bounds__(1024) void scanB(int* __restrict__ bsum, int nb) {
  __shared__ int s[1024];
  int tid = threadIdx.x;
  int v = (tid < nb) ? bsum[tid] : 0;
  s[tid] = v;
  __syncthreads();
  for (int st = 1; st < 1024; st <<= 1) {
    int x = (tid >= st) ? s[tid - st] : 0;
    __syncthreads();
    s[tid] += x;
    __syncthreads();
  }
  if (tid < nb) bsum[tid] = s[tid] - v;
}

__global__ __launch_bounds__(1024) void scanC(int* __restrict__ off,
                                              int* __restrict__ cursor,
                                              const int* __restrict__ bsum,
                                              int M, int E) {
  int i = blockIdx.x * 1024 + threadIdx.x;
  if (i < M) {
    int o = off[i] + bsum[blockIdx.x];
    off[i] = o;
    cursor[i] = o;
  }
  if (i == 0) off[M] = E;
}

// ---------------- place edges into (dst, r)-sorted slots ----------------
// meta: x = src, y = 1/cnt(dst,r). Contention profile identical to the proven
// r0/r1 place (~32 RMWs/line on cursor, 8B scattered meta writes).
__global__ void place_kernel(const int* __restrict__ ei, const int* __restrict__ et,
                             const int* __restrict__ cnt, int* __restrict__ cursor,
                             int2* __restrict__ meta, int E) {
  int e = blockIdx.x * blockDim.x + threadIdx.x;
  if (e >= E) return;
  int src = ei[e], dst = ei[E + e], r = et[e];
  int seg = dst * R_ET + r;
  int slot = atomicAdd(&cursor[seg], 1);
  meta[slot] = make_int2(src, __float_as_int(1.f / (float)cnt[seg]));
}

// ------- stacked weight convert: Wt[n][k], k = r*128+kin (r<8) or 1024+kin (root) ----
__global__ __launch_bounds__(256) void wconv_kernel(const float* __restrict__ root,
                                                    const float* __restrict__ W,
                                                    ushort* __restrict__ Wt) {
  int mat = blockIdx.x;  // 0..7 = W[r], 8 = root
  const float* src = (mat == 8) ? root : (W + (size_t)mat * DH * DH);
  for (int idx = threadIdx.x; idx < DH * DH; idx += 256) {
    int n = idx >> 7, kin = idx & 127;
    int k = mat * DH + kin;
    Wt[(size_t)n * KST + (((k >> 3) ^ (n & 7)) << 3) + (k & 7)] = f2bf(src[kin * DH + n]);
  }
}

// ---------------- activation convert (layer 0), zero-pads rows, swizzled ----------------
__global__ __launch_bounds__(256) void aconv_kernel(const float* __restrict__ src,
                                                    ushort* __restrict__ dst,
                                                    int total, int padtotal) {
  int i4 = (blockIdx.x * 256 + threadIdx.x) * 4;
  if (i4 >= padtotal) return;
  int row = i4 >> 7, k = i4 & 127;
  ushort4 o = make_ushort4(0, 0, 0, 0);
  if (i4 < total) {
    float4 v = *(const float4*)&src[i4];
    o = make_ushort4(f2bf(v.x), f2bf(v.y), f2bf(v.z), f2bf(v.w));
  }
  *(ushort4*)&dst[(size_t)row * DH + (((k >> 3) ^ (row & 7)) << 3) + (k & 7)] = o;
}

// ============== fused RGCN layer: register aggregation + K=1152 MFMA GEMM ===========
// Block = 32 dsts, 512 threads (8 waves). Each wave aggregates 4 dsts: per (dst,r)
// CSR segment, wave-wide shfl-broadcast edge loop, 2 fp32 accumulators per lane
// (lane = 2 feature cols), bf16 result into the G-tile [32][1152] in LDS; root
// block is a straight copy of the dst's own row. Then GEMM G x Wt_stacked
// (L2-hot, per-fragment global reads). acc layout: mfma(B,A) swapped operands ->
// lane l15 = dst row, quad*4+reg = output col.
__global__ __launch_bounds__(512, 4) void rgcn_layer(
    const ushort* __restrict__ Ain, const int* __restrict__ off2,
    const int2* __restrict__ meta, const ushort* __restrict__ Wt,
    const float* __restrict__ bias, ushort* __restrict__ Aout,
    float* __restrict__ pbuf, int N, int last) {
  __shared__ ushort G[32 * KST];  // 72 KB
  __shared__ float sb[DH];
  const int tid = threadIdx.x;
  const int wave = tid >> 6, lane = tid & 63;
  const int quad = lane >> 4, l15 = lane & 15;
  const int kb = lane >> 2;        // 16B-block index for k = lane*2
  const int klo = (lane * 2) & 7;  // within-block element
  const int rbase = blockIdx.x * 32;

  // ---- aggregation: wave handles dsts ld = wave*4 .. wave*4+3 ----
  for (int dd = 0; dd < 4; dd++) {
    const int ld = wave * 4 + dd, gd = rbase + ld;
    const int swz = (ld & 7);
    int offv = 0;
    if (gd < N && lane < 9) offv = off2[gd * R_ET + lane];
    for (int r = 0; r < R_ET; r++) {
      int s0 = __shfl(offv, r), s1 = __shfl(offv, r + 1);
      float ax = 0.f, ay = 0.f;
      for (int base = s0; base < s1; base += 64) {
        int m = min(64, s1 - base);
        int2 md = make_int2(0, 0);
        if (lane < m) md = meta[base + lane];
        int j = 0;
        for (; j + 4 <= m; j += 4) {
          int p0 = __shfl(md.x, j),     p1 = __shfl(md.x, j + 1);
          int p2 = __shfl(md.x, j + 2), p3 = __shfl(md.x, j + 3);
          float c0 = __int_as_float(__shfl(md.y, j));
          float c1 = __int_as_float(__shfl(md.y, j + 1));
          float c2 = __int_as_float(__shfl(md.y, j + 2));
          float c3 = __int_as_float(__shfl(md.y, j + 3));
          unsigned v0 = *(const unsigned*)&Ain[((size_t)p0 << 7) + ((kb ^ (p0 & 7)) << 3) + klo];
          unsigned v1 = *(const unsigned*)&Ain[((size_t)p1 << 7) + ((kb ^ (p1 & 7)) << 3) + klo];
          unsigned v2 = *(const unsigned*)&Ain[((size_t)p2 << 7) + ((kb ^ (p2 & 7)) << 3) + klo];
          unsigned v3 = *(const unsigned*)&Ain[((size_t)p3 << 7) + ((kb ^ (p3 & 7)) << 3) + klo];
          ax = fmaf(__uint_as_float(v0 << 16), c0, ax);
          ay = fmaf(__uint_as_float(v0 & 0xffff0000u), c0, ay);
          ax = fmaf(__uint_as_float(v1 << 16), c1, ax);
          ay = fmaf(__uint_as_float(v1 & 0xffff0000u), c1, ay);
          ax = fmaf(__uint_as_float(v2 << 16), c2, ax);
          ay = fmaf(__uint_as_float(v2 & 0xffff0000u), c2, ay);
          ax = fmaf(__uint_as_float(v3 << 16), c3, ax);
          ay = fmaf(__uint_as_float(v3 & 0xffff0000u), c3, ay);
        }
        for (; j < m; j++) {
          int p = __shfl(md.x, j);
          float c = __int_as_float(__shfl(md.y, j));
          unsigned v = *(const unsigned*)&Ain[((size_t)p << 7) + ((kb ^ (p & 7)) << 3) + klo];
          ax = fmaf(__uint_as_float(v << 16), c, ax);
          ay = fmaf(__uint_as_float(v & 0xffff0000u), c, ay);
        }
      }
      unsigned o = (unsigned)f2bf(ax) | ((unsigned)f2bf(ay) << 16);
      *(unsigned*)&G[ld * KST + (((r * 16 + kb) ^ swz) << 3) + klo] = o;
    }
    // root block: copy own row (pad rows read zeros; (gd&7)==(ld&7) since rbase%32==0)
    unsigned v = *(const unsigned*)&Ain[((size_t)gd << 7) + ((kb ^ swz) << 3) + klo];
    *(unsigned*)&G[ld * KST + (((128 + kb) ^ swz) << 3) + klo] = v;
  }
  __syncthreads();

  // ---- GEMM: [32 x 1152] (LDS) x [1152 x 128] (global, L2-hot) ----
  f32x4 acc0 = (f32x4){0.f, 0.f, 0.f, 0.f};
  f32x4 acc1 = (f32x4){0.f, 0.f, 0.f, 0.f};
  const int n = wave * 16 + l15;
  const ushort* Wn = Wt + (size_t)n * KST;
  const int nx = n & 7, rx = l15 & 7;
#pragma unroll
  for (int t = 0; t < KST / 32; t++) {
    int b8 = t * 4 + quad;
    bf16x8 a0 = *(const bf16x8*)&G[l15 * KST + ((b8 ^ rx) << 3)];
    bf16x8 a1 = *(const bf16x8*)&G[(16 + l15) * KST + ((b8 ^ rx) << 3)];
    bf16x8 bw = *(const bf16x8*)&Wn[(b8 ^ nx) << 3];
    acc0 = __builtin_amdgcn_mfma_f32_16x16x32_bf16(bw, a0, acc0, 0, 0, 0);
    acc1 = __builtin_amdgcn_mfma_f32_16x16x32_bf16(bw, a1, acc1, 0, 0, 0);
  }

  // ---- epilogue ----
  if (!last) {
    const int c0 = wave * 16 + quad * 4;
    float4 bv = *(const float4*)&bias[c0];
#pragma unroll
    for (int i = 0; i < 2; i++) {
      const f32x4& a = i ? acc1 : acc0;
      int node = rbase + i * 16 + l15;
      unsigned lo = 0, hi = 0;
      if (node < N) {
        lo = (unsigned)f2bf(fmaxf(a[0] + bv.x, 0.f)) |
             ((unsigned)f2bf(fmaxf(a[1] + bv.y, 0.f)) << 16);
        hi = (unsigned)f2bf(fmaxf(a[2] + bv.z, 0.f)) |
             ((unsigned)f2bf(fmaxf(a[3] + bv.w, 0.f)) << 16);
      }
      // pad rows written as zeros so next layer's root-copy reads zeros
      *(uint2*)&Aout[(size_t)node * DH + (((c0 >> 3) ^ (node & 7)) << 3) + (c0 & 7)] =
          make_uint2(lo, hi);
    }
  } else {
    // column partial sums for the mean pool (bias folded into mlp)
    f32x4 s;
#pragma unroll
    for (int c = 0; c < 4; c++) s[c] = acc0[c] + acc1[c];
#pragma unroll
    for (int mask = 1; mask < 16; mask <<= 1)
#pragma unroll
      for (int c = 0; c < 4; c++) s[c] += __shfl_xor(s[c], mask);
    if (l15 == 0) {
      int c0 = wave * 16 + quad * 4;
#pragma unroll
      for (int c = 0; c < 4; c++) sb[c0 + c] = s[c];  // unique writer per col
    }
    __syncthreads();
    if (tid < DH) pbuf[(size_t)blockIdx.x * DH + tid] = sb[tid];
  }
}

// ---------------- reduce per-block partials -> u ----------------
__global__ __launch_bounds__(256) void pool_reduce(const float* __restrict__ pbuf,
                                                   float* __restrict__ u, int nblk) {
  __shared__ float s[256];
  int tid = threadIdx.x;
  int c = tid & 127, h = tid >> 7;
  int chunk = (nblk + gridDim.x - 1) / gridDim.x;
  int r0 = blockIdx.x * chunk;
  int r1 = min(r0 + chunk, nblk);
  float sum = 0.f;
  for (int r = r0 + h; r < r1; r += 2) sum += pbuf[(size_t)r * 128 + c];
  s[tid] = sum;
  __syncthreads();
  if (tid < 128) atomicAdd(&u[c], s[tid] + s[tid + 128]);
}

// ---------------- final MLP on concat(u1/N + b2, u2/N + b2) ----------------
__global__ __launch_bounds__(256) void mlp_kernel(
    const float* __restrict__ u, const float* __restrict__ b2,
    const float* __restrict__ fc1w, const float* __restrict__ fc1b,
    const float* __restrict__ fc2w, const float* __restrict__ fc2b,
    float* __restrict__ out, int N) {
  __shared__ float uin[256];
  __shared__ float hred[128];
  int tid = threadIdx.x;
  uin[tid] = u[tid] * (1.f / (float)N) + b2[tid & 127];
  __syncthreads();
  if (tid < 128) {
    float s = fc1b[tid];
    for (int i = 0; i < 256; i++) s = fmaf(uin[i], fc1w[i * 128 + tid], s);
    s = fmaxf(s, 0.f);
    hred[tid] = s * fc2w[tid];
  }
  __syncthreads();
  if (tid == 0) {
    float s = fc2b[0];
    for (int i = 0; i < 128; i++) s += hred[i];
    out[0] = s;
  }
}

extern "C" void kernel_launch(void* const* d_in, const int* in_sizes, int n_in,
                              void* d_out, int out_size, void* d_ws, size_t ws_size,
                              hipStream_t stream) {
  const float* x[2] = {(const float*)d_in[0], (const float*)d_in[3]};
  const int* ei[2] = {(const int*)d_in[1], (const int*)d_in[4]};
  const int* et[2] = {(const int*)d_in[2], (const int*)d_in[5]};
  const float* Wp[3] = {(const float*)d_in[6], (const float*)d_in[9], (const float*)d_in[12]};
  const float* rootp[3] = {(const float*)d_in[7], (const float*)d_in[10], (const float*)d_in[13]};
  const float* biasp[3] = {(const float*)d_in[8], (const float*)d_in[11], (const float*)d_in[14]};
  const float* fc1w = (const float*)d_in[15];
  const float* fc1b = (const float*)d_in[16];
  const float* fc2w = (const float*)d_in[17];
  const float* fc2b = (const float*)d_in[18];

  const int N = in_sizes[0] / DH;
  const int E = in_sizes[2];
  const int Npad = (N + 127) & ~127;   // A-buffer rows (zero-padded by aconv/epilogue)
  const int nt2 = (N + 31) / 32;       // rgcn_layer blocks (32 dsts each)
  const int M = N * R_ET;              // (dst, r) segments
  const int MB = (M + 1023) / 1024;    // scan blocks (<=1024)

  char* ws = (char*)d_ws;
  size_t ob = 0;
  auto alloc = [&](size_t bytes) {
    void* p = ws + ob;
    ob = (ob + bytes + 255) & ~(size_t)255;
    return p;
  };
  int* cnt2 = (int*)alloc((size_t)M * 4);
  int* off2 = (int*)alloc((size_t)(M + 1) * 4);
  int* cursor2 = (int*)alloc((size_t)M * 4);
  int* bsum = (int*)alloc(1024 * 4);
  int2* meta = (int2*)alloc((size_t)E * 8);
  float* u = (float*)alloc(1024);
  float* pbuf = (float*)alloc((size_t)nt2 * DH * 4);
  ushort* A0 = (ushort*)alloc((size_t)Npad * DH * 2);
  ushort* A1 = (ushort*)alloc((size_t)Npad * DH * 2);
  ushort* Wt = (ushort*)alloc((size_t)3 * DH * KST * 2);
  (void)ws_size;

  hipMemsetAsync(u, 0, 2 * DH * sizeof(float), stream);
  for (int l = 0; l < 3; l++)
    wconv_kernel<<<9, 256, 0, stream>>>(rootp[l], Wp[l], Wt + (size_t)l * DH * KST);

  dim3 egrid((E + 255) / 256);
  const int total = N * DH, padtotal = Npad * DH;
  dim3 agrid((padtotal / 4 + 255) / 256);

  for (int g = 0; g < 2; g++) {
    hipMemsetAsync(cnt2, 0, (size_t)M * sizeof(int), stream);
    count_kernel<<<egrid, 256, 0, stream>>>(ei[g], et[g], cnt2, E);
    scanA<<<MB, 1024, 0, stream>>>(cnt2, off2, bsum, M);
    scanB<<<1, 1024, 0, stream>>>(bsum, MB);
    scanC<<<MB, 1024, 0, stream>>>(off2, cursor2, bsum, M, E);
    place_kernel<<<egrid, 256, 0, stream>>>(ei[g], et[g], cnt2, cursor2, meta, E);
    aconv_kernel<<<agrid, 256, 0, stream>>>(x[g], A0, total, padtotal);

    rgcn_layer<<<nt2, 512, 0, stream>>>(A0, off2, meta, Wt, biasp[0], A1, nullptr, N, 0);
    rgcn_layer<<<nt2, 512, 0, stream>>>(A1, off2, meta, Wt + (size_t)DH * KST,
                                        biasp[1], A0, nullptr, N, 0);
    rgcn_layer<<<nt2, 512, 0, stream>>>(A0, off2, meta, Wt + (size_t)2 * DH * KST,
                                        biasp[2], nullptr, pbuf, N, 1);
    pool_reduce<<<100, 256, 0, stream>>>(pbuf, u + g * DH, nt2);
  }
  mlp_kernel<<<1, 256, 0, stream>>>(u, biasp[2], fc1w, fc1b, fc2w, fc2b,
                                    (float*)d_out, N);
}